// Round 5
// baseline (53.582 us; speedup 1.0000x reference)
//
#include <hip/hip_runtime.h>
#include <math.h>

#define LMAX 50
#define NB   4096
#define NROW (NB * LMAX)     // 204800 padded rows
#define RPW  64              // rows per wave in kernel A (4 m-tiles of 16)

typedef short bf16x8 __attribute__((ext_vector_type(8)));
typedef float f32x4  __attribute__((ext_vector_type(4)));

union bfu { bf16x8 v; unsigned u[4]; };

// packed f32 pair -> 2x bf16 (RNE), single VALU instr
__device__ __forceinline__ unsigned cvt_pk(float lo, float hi) {
    unsigned r;
    asm("v_cvt_pk_bf16_f32 %0, %1, %2" : "=v"(r) : "v"(lo), "v"(hi));
    return r;
}
__device__ __forceinline__ bf16x8 cvt8f(float4 a, float4 b) {
    bfu r;
    r.u[0] = cvt_pk(a.x, a.y); r.u[1] = cvt_pk(a.z, a.w);
    r.u[2] = cvt_pk(b.x, b.y); r.u[3] = cvt_pk(b.z, b.w);
    return r.v;
}

// ---------------- Kernel A: dense padded MLP -> logits ----------------
// One wave = 64 consecutive padded rows = 4 independent 16-row m-tiles.
// Row rr -> element b = rr/50. Padding rows produce garbage logits that
// kernel B never reads. All weight fragments VGPR-resident.
__global__ __launch_bounds__(512, 3) void mlp_logits_k(
    const float* __restrict__ u_table, const float* __restrict__ i_table,
    const float* __restrict__ W1, const float* __restrict__ b1,
    const float* __restrict__ W2, const float* __restrict__ b2,
    const float* __restrict__ W3,
    const int* __restrict__ nodes, const int* __restrict__ neighbors,
    float* __restrict__ logits)
{
    // cooperative staging of B-fragments: frag f, lane(l15,g) holds
    // B[k][n], n = nt*16+l15, k = ks*32 + g*8 + i
    __shared__ __attribute__((aligned(16))) short WL[24][64][8];            // 24.5 KB
    __shared__ __attribute__((aligned(16))) unsigned short Hs[8][16 * 72];  // 18.4 KB

    const int tid  = threadIdx.x;
    const int w    = tid >> 6, lane = tid & 63;
    const int l15  = lane & 15, g = lane >> 4, g8 = g * 8;

    for (int f = w; f < 24; f += 8) {
        const float* Ws = (f < 16) ? W1 : W2;
        const int    fi = (f < 16) ? f : f - 16;
        const int    ks = fi >> 2, nt = fi & 3;
        const float* p  = Ws + (ks * 32 + g8) * 64 + nt * 16 + l15;
        bfu r;
        r.u[0] = cvt_pk(p[0 * 64], p[1 * 64]);
        r.u[1] = cvt_pk(p[2 * 64], p[3 * 64]);
        r.u[2] = cvt_pk(p[4 * 64], p[5 * 64]);
        r.u[3] = cvt_pk(p[6 * 64], p[7 * 64]);
        *(bf16x8*)&WL[f][lane][0] = r.v;
    }
    __syncthreads();

    // pull all 24 fragments into VGPRs (one b128 each)
    bf16x8 w1f[4][4], w2f[2][4];
    #pragma unroll
    for (int ks = 0; ks < 4; ++ks)
        #pragma unroll
        for (int nt = 0; nt < 4; ++nt)
            w1f[ks][nt] = *(const bf16x8*)&WL[ks * 4 + nt][lane][0];
    #pragma unroll
    for (int ks = 0; ks < 2; ++ks)
        #pragma unroll
        for (int nt = 0; nt < 4; ++nt)
            w2f[ks][nt] = *(const bf16x8*)&WL[16 + ks * 4 + nt][lane][0];

    float b1v[4], b2v[4], w3v[4];
    #pragma unroll
    for (int nt = 0; nt < 4; ++nt) {
        b1v[nt] = b1[nt * 16 + l15];
        b2v[nt] = b2[nt * 16 + l15];
        w3v[nt] = W3[nt * 16 + l15];
    }
    // b3 is softmax-invariant; skip.

    const int base = (blockIdx.x * 8 + w) * RPW;
    unsigned short* hw = &Hs[w][0];

    #pragma unroll
    for (int mt = 0; mt < 4; ++mt) {
        const int rr   = base + mt * 16 + l15;        // this lane's A-row
        const unsigned bb = (unsigned)rr / 50u;       // element id (magic mul)
        const int nbr  = neighbors[rr];
        const int node = nodes[bb];

        const float* xp = i_table + (size_t)nbr * 64;
        const float* up = u_table + (size_t)node * 64;
        float4 x0 = *(const float4*)(xp + g8);
        float4 x1 = *(const float4*)(xp + g8 + 4);
        float4 x2 = *(const float4*)(xp + 32 + g8);
        float4 x3 = *(const float4*)(xp + 32 + g8 + 4);
        float4 u0 = *(const float4*)(up + g8);
        float4 u1 = *(const float4*)(up + g8 + 4);
        float4 u2 = *(const float4*)(up + 32 + g8);
        float4 u3 = *(const float4*)(up + 32 + g8 + 4);

        bf16x8 a0  = cvt8f(x0, x1), a1  = cvt8f(x2, x3);
        bf16x8 au0 = cvt8f(u0, u1), au1 = cvt8f(u2, u3);

        // ---- layer 1: K=128 ([x | xu] @ W1 + b1), relu ----
        f32x4 acc[4];
        #pragma unroll
        for (int nt = 0; nt < 4; ++nt)
            acc[nt] = (f32x4){b1v[nt], b1v[nt], b1v[nt], b1v[nt]};
        #pragma unroll
        for (int nt = 0; nt < 4; ++nt)
            acc[nt] = __builtin_amdgcn_mfma_f32_16x16x32_bf16(a0,  w1f[0][nt], acc[nt], 0, 0, 0);
        #pragma unroll
        for (int nt = 0; nt < 4; ++nt)
            acc[nt] = __builtin_amdgcn_mfma_f32_16x16x32_bf16(a1,  w1f[1][nt], acc[nt], 0, 0, 0);
        #pragma unroll
        for (int nt = 0; nt < 4; ++nt)
            acc[nt] = __builtin_amdgcn_mfma_f32_16x16x32_bf16(au0, w1f[2][nt], acc[nt], 0, 0, 0);
        #pragma unroll
        for (int nt = 0; nt < 4; ++nt)
            acc[nt] = __builtin_amdgcn_mfma_f32_16x16x32_bf16(au1, w1f[3][nt], acc[nt], 0, 0, 0);

        // relu -> bf16 -> per-wave LDS transpose (C: row g*4+reg, col nt*16+l15)
        #pragma unroll
        for (int nt = 0; nt < 4; ++nt) {
            unsigned p0 = cvt_pk(fmaxf(acc[nt][0], 0.f), fmaxf(acc[nt][1], 0.f));
            unsigned p1 = cvt_pk(fmaxf(acc[nt][2], 0.f), fmaxf(acc[nt][3], 0.f));
            hw[(g * 4 + 0) * 72 + nt * 16 + l15] = (unsigned short)p0;
            hw[(g * 4 + 1) * 72 + nt * 16 + l15] = (unsigned short)(p0 >> 16);
            hw[(g * 4 + 2) * 72 + nt * 16 + l15] = (unsigned short)p1;
            hw[(g * 4 + 3) * 72 + nt * 16 + l15] = (unsigned short)(p1 >> 16);
        }
        bf16x8 h0 = *(const bf16x8*)&hw[l15 * 72 + g8];
        bf16x8 h1 = *(const bf16x8*)&hw[l15 * 72 + 32 + g8];

        // ---- layer 2 ----
        f32x4 c2[4];
        #pragma unroll
        for (int nt = 0; nt < 4; ++nt)
            c2[nt] = (f32x4){b2v[nt], b2v[nt], b2v[nt], b2v[nt]};
        #pragma unroll
        for (int nt = 0; nt < 4; ++nt)
            c2[nt] = __builtin_amdgcn_mfma_f32_16x16x32_bf16(h0, w2f[0][nt], c2[nt], 0, 0, 0);
        #pragma unroll
        for (int nt = 0; nt < 4; ++nt)
            c2[nt] = __builtin_amdgcn_mfma_f32_16x16x32_bf16(h1, w2f[1][nt], c2[nt], 0, 0, 0);

        // ---- layer 3 logits + write (rows g*4+reg) ----
        float sv[4];
        #pragma unroll
        for (int reg = 0; reg < 4; ++reg) {
            float s = 0.f;
            #pragma unroll
            for (int nt = 0; nt < 4; ++nt)
                s = fmaf(fmaxf(c2[nt][reg], 0.f), w3v[nt], s);
            s += __shfl_xor(s, 1); s += __shfl_xor(s, 2);
            s += __shfl_xor(s, 4); s += __shfl_xor(s, 8);
            sv[reg] = s;
        }
        if (l15 == 0)
            *(float4*)&logits[base + mt * 16 + g * 4] =
                make_float4(sv[0], sv[1], sv[2], sv[3]);
    }
}

// ---------------- Kernel B: per-element softmax + weighted sum ----------------
__global__ __launch_bounds__(512) void softmax_agg_k(
    const float* __restrict__ i_table,
    const int* __restrict__ neighbors, const int* __restrict__ lengths,
    const float* __restrict__ logits, float* __restrict__ out)
{
    __shared__ float Es[8][64];
    const int tid  = threadIdx.x;
    const int w    = tid >> 6, lane = tid & 63;
    const int b    = blockIdx.x * 8 + w;
    const int len  = lengths[b];

    float lg = (lane < len) ? logits[b * LMAX + lane] : -INFINITY;
    float mx = lg;
    #pragma unroll
    for (int off = 1; off < 64; off <<= 1) mx = fmaxf(mx, __shfl_xor(mx, off));
    float e = (lane < len) ? __expf(lg - mx) : 0.f;
    float ss = e;
    #pragma unroll
    for (int off = 1; off < 64; off <<= 1) ss += __shfl_xor(ss, off);
    Es[w][lane] = e;   // same-wave LDS write->read is ordered (lgkmcnt)

    float ac0 = 0.f, ac1 = 0.f, ac2 = 0.f, ac3 = 0.f;
    const int* nb = neighbors + b * LMAX;
    for (int r0 = 0; r0 < len; r0 += 4) {
        float e0 = 0.f, e1 = 0.f, e2 = 0.f, e3 = 0.f;
        float x0 = 0.f, x1 = 0.f, x2 = 0.f, x3 = 0.f;
        { e0 = Es[w][r0];     x0 = i_table[(size_t)nb[r0] * 64 + lane]; }
        if (r0 + 1 < len) { e1 = Es[w][r0 + 1]; x1 = i_table[(size_t)nb[r0 + 1] * 64 + lane]; }
        if (r0 + 2 < len) { e2 = Es[w][r0 + 2]; x2 = i_table[(size_t)nb[r0 + 2] * 64 + lane]; }
        if (r0 + 3 < len) { e3 = Es[w][r0 + 3]; x3 = i_table[(size_t)nb[r0 + 3] * 64 + lane]; }
        ac0 = fmaf(e0, x0, ac0); ac1 = fmaf(e1, x1, ac1);
        ac2 = fmaf(e2, x2, ac2); ac3 = fmaf(e3, x3, ac3);
    }
    out[b * 64 + lane] = ((ac0 + ac1) + (ac2 + ac3)) / ss;
}

extern "C" void kernel_launch(void* const* d_in, const int* in_sizes, int n_in,
                              void* d_out, int out_size, void* d_ws, size_t ws_size,
                              hipStream_t stream) {
    const float* u_table   = (const float*)d_in[0];
    const float* i_table   = (const float*)d_in[1];
    const float* W1        = (const float*)d_in[2];
    const float* b1        = (const float*)d_in[3];
    const float* W2        = (const float*)d_in[4];
    const float* b2        = (const float*)d_in[5];
    const float* W3        = (const float*)d_in[6];
    // d_in[7] = b3: softmax-invariant, unused
    const int*   nodes     = (const int*)d_in[8];
    const int*   neighbors = (const int*)d_in[9];
    const int*   lengths   = (const int*)d_in[10];
    float* out    = (float*)d_out;
    float* logits = (float*)d_ws;           // 204800 * 4 B = 819 KB scratch

    mlp_logits_k<<<dim3(NROW / RPW / 8), dim3(512), 0, stream>>>(
        u_table, i_table, W1, b1, W2, b2, W3, nodes, neighbors, logits);
    softmax_agg_k<<<dim3(NB / 8), dim3(512), 0, stream>>>(
        i_table, neighbors, lengths, logits, out);
}

// Round 6
// 22.835 us; speedup vs baseline: 2.3465x; 2.3465x over previous
//
#include <hip/hip_runtime.h>
#include <math.h>

#define LMAX  50
#define NWAVE 2048     // 512 blocks x 4 waves; each wave: elements wid, wid+2048

typedef short bf16x8 __attribute__((ext_vector_type(8)));
typedef float f32x4  __attribute__((ext_vector_type(4)));
union bfu { bf16x8 v; unsigned u[4]; };

// packed f32 pair -> 2x bf16 (RNE), single VALU instr
__device__ __forceinline__ unsigned cvt_pk(float lo, float hi) {
    unsigned r;
    asm("v_cvt_pk_bf16_f32 %0, %1, %2" : "=v"(r) : "v"(lo), "v"(hi));
    return r;
}
__device__ __forceinline__ bf16x8 cvt8f(float4 a, float4 b) {
    bfu r;
    r.u[0] = cvt_pk(a.x, a.y); r.u[1] = cvt_pk(a.z, a.w);
    r.u[2] = cvt_pk(b.x, b.y); r.u[3] = cvt_pk(b.z, b.w);
    return r.v;
}

// one batch element: MLP logits (MFMA) + online softmax + fragment-based
// weighted sum. idx[0..3] preloaded (clamped); axu = node fragments.
__device__ __forceinline__ void process_elem(
    const float* __restrict__ i_table, float* __restrict__ out,
    int b, int len, const int (&idx)[6],
    bf16x8 axu0, bf16x8 axu1,
    const bf16x8 (&w1f)[4][4], const bf16x8 (&w2f)[2][4],
    const float (&b1v)[4], const float (&b2v)[4], const float (&w3v)[4],
    unsigned short* __restrict__ hw, float* __restrict__ Lsw,
    int l15, int g)
{
    const int g8    = g * 8;
    const int ntile = (len + 15) >> 4;

    float4 LA[2][4];   // 2-deep rolling gather buffers (static indexing only)
    #define ISSUE_T(t) if ((t) < ntile) { \
        const float* xp = i_table + (size_t)idx[t] * 64 + g8; \
        LA[(t) & 1][0] = *(const float4*)(xp); \
        LA[(t) & 1][1] = *(const float4*)(xp + 4); \
        LA[(t) & 1][2] = *(const float4*)(xp + 32); \
        LA[(t) & 1][3] = *(const float4*)(xp + 36); \
    }
    ISSUE_T(0)
    ISSUE_T(1)

    // ---- node half of layer 1 (identical for all rows): hn = b1 + xu@W1n ----
    f32x4 hn[4];
    #pragma unroll
    for (int nt = 0; nt < 4; ++nt)
        hn[nt] = (f32x4){b1v[nt], b1v[nt], b1v[nt], b1v[nt]};
    #pragma unroll
    for (int nt = 0; nt < 4; ++nt)
        hn[nt] = __builtin_amdgcn_mfma_f32_16x16x32_bf16(axu0, w1f[2][nt], hn[nt], 0, 0, 0);
    #pragma unroll
    for (int nt = 0; nt < 4; ++nt)
        hn[nt] = __builtin_amdgcn_mfma_f32_16x16x32_bf16(axu1, w1f[3][nt], hn[nt], 0, 0, 0);

    float m = -INFINITY, ssum = 0.f;
    float accW[16];
    #pragma unroll
    for (int i = 0; i < 16; ++i) accW[i] = 0.f;

    #pragma unroll
    for (int t = 0; t < 4; ++t) {
        if (t < ntile) {
            bf16x8 a0 = cvt8f(LA[t & 1][0], LA[t & 1][1]);
            bf16x8 a1 = cvt8f(LA[t & 1][2], LA[t & 1][3]);
            if (t + 2 < 4) ISSUE_T(t + 2)     // both conditions fold at compile time

            // ---- layer 1 (neighbor half), K=64 on top of hn ----
            f32x4 acc[4];
            #pragma unroll
            for (int nt = 0; nt < 4; ++nt) acc[nt] = hn[nt];
            #pragma unroll
            for (int nt = 0; nt < 4; ++nt)
                acc[nt] = __builtin_amdgcn_mfma_f32_16x16x32_bf16(a0, w1f[0][nt], acc[nt], 0, 0, 0);
            #pragma unroll
            for (int nt = 0; nt < 4; ++nt)
                acc[nt] = __builtin_amdgcn_mfma_f32_16x16x32_bf16(a1, w1f[1][nt], acc[nt], 0, 0, 0);

            // relu -> bf16 -> per-wave LDS transpose (C: row g*4+reg, col nt*16+l15)
            #pragma unroll
            for (int nt = 0; nt < 4; ++nt) {
                unsigned p0 = cvt_pk(fmaxf(acc[nt][0], 0.f), fmaxf(acc[nt][1], 0.f));
                unsigned p1 = cvt_pk(fmaxf(acc[nt][2], 0.f), fmaxf(acc[nt][3], 0.f));
                hw[(g * 4 + 0) * 72 + nt * 16 + l15] = (unsigned short)p0;
                hw[(g * 4 + 1) * 72 + nt * 16 + l15] = (unsigned short)(p0 >> 16);
                hw[(g * 4 + 2) * 72 + nt * 16 + l15] = (unsigned short)p1;
                hw[(g * 4 + 3) * 72 + nt * 16 + l15] = (unsigned short)(p1 >> 16);
            }
            bf16x8 h0 = *(const bf16x8*)&hw[l15 * 72 + g8];
            bf16x8 h1 = *(const bf16x8*)&hw[l15 * 72 + 32 + g8];

            // ---- layer 2 ----
            f32x4 c2[4];
            #pragma unroll
            for (int nt = 0; nt < 4; ++nt)
                c2[nt] = (f32x4){b2v[nt], b2v[nt], b2v[nt], b2v[nt]};
            #pragma unroll
            for (int nt = 0; nt < 4; ++nt)
                c2[nt] = __builtin_amdgcn_mfma_f32_16x16x32_bf16(h0, w2f[0][nt], c2[nt], 0, 0, 0);
            #pragma unroll
            for (int nt = 0; nt < 4; ++nt)
                c2[nt] = __builtin_amdgcn_mfma_f32_16x16x32_bf16(h1, w2f[1][nt], c2[nt], 0, 0, 0);

            // ---- layer 3 logits (row g*4+reg), reduce over n within group ----
            float sv[4];
            #pragma unroll
            for (int reg = 0; reg < 4; ++reg) {
                float s = 0.f;
                #pragma unroll
                for (int nt = 0; nt < 4; ++nt)
                    s = fmaf(fmaxf(c2[nt][reg], 0.f), w3v[nt], s);
                s += __shfl_xor(s, 1); s += __shfl_xor(s, 2);
                s += __shfl_xor(s, 4); s += __shfl_xor(s, 8);
                if (t * 16 + g * 4 + reg >= len) s = -INFINITY;
                sv[reg] = s;
            }

            // ---- online softmax (wave-uniform running state) ----
            float tm = fmaxf(fmaxf(sv[0], sv[1]), fmaxf(sv[2], sv[3]));
            tm = fmaxf(tm, __shfl_xor(tm, 16));
            tm = fmaxf(tm, __shfl_xor(tm, 32));
            if (tm > m) {
                const float nm = tm;
                const float sc = __expf(m - nm);   // first tile: exp(-inf)=0
                ssum *= sc;
                #pragma unroll
                for (int i = 0; i < 16; ++i) accW[i] *= sc;
                m = nm;
            }
            float e0 = __expf(sv[0] - m), e1 = __expf(sv[1] - m);
            float e2 = __expf(sv[2] - m), e3 = __expf(sv[3] - m);
            float es = (e0 + e1) + (e2 + e3);
            es += __shfl_xor(es, 16);
            es += __shfl_xor(es, 32);
            ssum += es;

            // broadcast e to row owners via per-wave LDS
            if (l15 == 0) *(float4*)&Lsw[g * 4] = make_float4(e0, e1, e2, e3);
            const float er = Lsw[l15];             // e for tile row l15

            // weighted-x partials straight from the A-fragments (bf16->f32 shift)
            #pragma unroll
            for (int i = 0; i < 8; ++i) {
                union { unsigned u; float f; } lo, hi2;
                lo.u  = ((unsigned)(unsigned short)a0[i]) << 16;
                hi2.u = ((unsigned)(unsigned short)a1[i]) << 16;
                accW[i]     = fmaf(er, lo.f,  accW[i]);
                accW[8 + i] = fmaf(er, hi2.f, accW[8 + i]);
            }
        }
    }
    #undef ISSUE_T

    // ---- finalize: reduce over the 16 tile rows (l15), write 64 dims ----
    #pragma unroll
    for (int i = 0; i < 16; ++i) {
        accW[i] += __shfl_xor(accW[i], 1);
        accW[i] += __shfl_xor(accW[i], 2);
        accW[i] += __shfl_xor(accW[i], 4);
        accW[i] += __shfl_xor(accW[i], 8);
    }
    const float inv = 1.f / ssum;
    if (l15 == 0) {
        float4 o0 = make_float4(accW[0] * inv,  accW[1] * inv,  accW[2] * inv,  accW[3] * inv);
        float4 o1 = make_float4(accW[4] * inv,  accW[5] * inv,  accW[6] * inv,  accW[7] * inv);
        float4 o2 = make_float4(accW[8] * inv,  accW[9] * inv,  accW[10] * inv, accW[11] * inv);
        float4 o3 = make_float4(accW[12] * inv, accW[13] * inv, accW[14] * inv, accW[15] * inv);
        *(float4*)(out + b * 64 +      g8)     = o0;
        *(float4*)(out + b * 64 +      g8 + 4) = o1;
        *(float4*)(out + b * 64 + 32 + g8)     = o2;
        *(float4*)(out + b * 64 + 32 + g8 + 4) = o3;
    }
}

__global__ __launch_bounds__(256, 2) void graphrec_k(
    const float* __restrict__ u_table, const float* __restrict__ i_table,
    const float* __restrict__ W1, const float* __restrict__ b1,
    const float* __restrict__ W2, const float* __restrict__ b2,
    const float* __restrict__ W3, const float* __restrict__ b3,
    const int* __restrict__ nodes, const int* __restrict__ neighbors,
    const int* __restrict__ lengths, float* __restrict__ out)
{
    __shared__ __attribute__((aligned(16))) short WL[24][64][8];            // 24.5 KB
    __shared__ __attribute__((aligned(16))) unsigned short Hs[4][16 * 72];  //  9.2 KB
    __shared__ float Ls[4][16];

    const int tid  = threadIdx.x;
    const int w    = tid >> 6, lane = tid & 63;
    const int l15  = lane & 15, g = lane >> 4, g8 = g * 8;

    // ---- stage weights as B-fragments: lane(l15,g) holds B[k][n],
    //      n = nt*16+l15, k = ks*32 + g*8 + i ----
    for (int f = w; f < 24; f += 4) {
        const float* Ws = (f < 16) ? W1 : W2;
        const int    fi = (f < 16) ? f : f - 16;
        const int    ks = fi >> 2, nt = fi & 3;
        const float* p  = Ws + (ks * 32 + g8) * 64 + nt * 16 + l15;
        bfu r;
        r.u[0] = cvt_pk(p[0 * 64], p[1 * 64]);
        r.u[1] = cvt_pk(p[2 * 64], p[3 * 64]);
        r.u[2] = cvt_pk(p[4 * 64], p[5 * 64]);
        r.u[3] = cvt_pk(p[6 * 64], p[7 * 64]);
        *(bf16x8*)&WL[f][lane][0] = r.v;
    }
    __syncthreads();

    // pull all 24 fragments into VGPRs (persistent)
    bf16x8 w1f[4][4], w2f[2][4];
    #pragma unroll
    for (int ks = 0; ks < 4; ++ks)
        #pragma unroll
        for (int nt = 0; nt < 4; ++nt)
            w1f[ks][nt] = *(const bf16x8*)&WL[ks * 4 + nt][lane][0];
    #pragma unroll
    for (int ks = 0; ks < 2; ++ks)
        #pragma unroll
        for (int nt = 0; nt < 4; ++nt)
            w2f[ks][nt] = *(const bf16x8*)&WL[16 + ks * 4 + nt][lane][0];

    float b1v[4], b2v[4], w3v[4];
    #pragma unroll
    for (int nt = 0; nt < 4; ++nt) {
        b1v[nt] = b1[nt * 16 + l15];
        b2v[nt] = b2[nt * 16 + l15];
        w3v[nt] = W3[nt * 16 + l15];
    }
    // b3 shifts all logits equally -> softmax-invariant, skip.

    const int wid = blockIdx.x * 4 + w;
    const int b0  = wid, b1e = wid + NWAVE;

    // ---- both elements' prologue loads issued up-front (elem1 hidden
    //      under elem0's compute) ----
    const int len0 = lengths[b0], len1 = lengths[b1e];
    const int nd0  = nodes[b0],   nd1  = nodes[b1e];

    int idx0[6] = {0, 0, 0, 0, 0, 0}, idx1[6] = {0, 0, 0, 0, 0, 0};
    const int nt0 = (len0 + 15) >> 4, nt1 = (len1 + 15) >> 4;
    #pragma unroll
    for (int t = 0; t < 4; ++t) {
        int r = t * 16 + l15; if (r >= len0) r = len0 - 1;
        if (t < nt0) idx0[t] = neighbors[b0 * LMAX + r];
    }
    #pragma unroll
    for (int t = 0; t < 4; ++t) {
        int r = t * 16 + l15; if (r >= len1) r = len1 - 1;
        if (t < nt1) idx1[t] = neighbors[b1e * LMAX + r];
    }

    const float* up0 = u_table + (size_t)nd0 * 64 + g8;
    const float* up1 = u_table + (size_t)nd1 * 64 + g8;
    float4 U00 = *(const float4*)(up0);
    float4 U01 = *(const float4*)(up0 + 4);
    float4 U02 = *(const float4*)(up0 + 32);
    float4 U03 = *(const float4*)(up0 + 36);
    float4 U10 = *(const float4*)(up1);      // stays f32 until elem1 (in flight)
    float4 U11 = *(const float4*)(up1 + 4);
    float4 U12 = *(const float4*)(up1 + 32);
    float4 U13 = *(const float4*)(up1 + 36);

    process_elem(i_table, out, b0, len0, idx0,
                 cvt8f(U00, U01), cvt8f(U02, U03),
                 w1f, w2f, b1v, b2v, w3v, &Hs[w][0], &Ls[w][0], l15, g);

    process_elem(i_table, out, b1e, len1, idx1,
                 cvt8f(U10, U11), cvt8f(U12, U13),
                 w1f, w2f, b1v, b2v, w3v, &Hs[w][0], &Ls[w][0], l15, g);
}

extern "C" void kernel_launch(void* const* d_in, const int* in_sizes, int n_in,
                              void* d_out, int out_size, void* d_ws, size_t ws_size,
                              hipStream_t stream) {
    const float* u_table   = (const float*)d_in[0];
    const float* i_table   = (const float*)d_in[1];
    const float* W1        = (const float*)d_in[2];
    const float* b1        = (const float*)d_in[3];
    const float* W2        = (const float*)d_in[4];
    const float* b2        = (const float*)d_in[5];
    const float* W3        = (const float*)d_in[6];
    const float* b3        = (const float*)d_in[7];
    const int*   nodes     = (const int*)d_in[8];
    const int*   neighbors = (const int*)d_in[9];
    const int*   lengths   = (const int*)d_in[10];
    float* out = (float*)d_out;

    graphrec_k<<<dim3(NWAVE / 4), dim3(256), 0, stream>>>(
        u_table, i_table, W1, b1, W2, b2, W3, b3, nodes, neighbors, lengths, out);
}